// Round 1
// baseline (18005.849 us; speedup 1.0000x reference)
//
#include <hip/hip_runtime.h>
#include <hip/hip_bf16.h>

// SSNet: 2-layer flag-gated LSTM, persistent-state MFMA implementation.
// B=16384, T=32, IN=64, H=512, OUT=19.
// One WG (512 thr, 8 waves) per 64 batch rows; 256 WGs = 256 CUs; no grid sync.
// h0/h1 carried fp32 in VGPRs, c0/c1 fp32 streamed via d_ws, GEMM operands bf16.

#define T_STEPS 32
#define IN_F    64
#define HID     512
#define OUT_F   19
#define BW      64   // batch rows per WG

typedef short bf16x8 __attribute__((ext_vector_type(8)));   // 8 bf16 = 4 VGPRs
typedef float f32x4  __attribute__((ext_vector_type(4)));

__device__ __forceinline__ float fast_sig(float x) {
    // 1/(1+e^-x); saturates cleanly: exp->inf => rcp->0, exp->0 => 1
    return __builtin_amdgcn_rcpf(1.0f + __expf(-x));
}
__device__ __forceinline__ float fast_tanh(float x) {
    // tanh = 1 - 2/(e^{2x}+1); exact saturation at +/-1 for |x| large
    return 1.0f - 2.0f * __builtin_amdgcn_rcpf(1.0f + __expf(2.0f * x));
}

// dst[n*K + k] = bf16(src[(k+rowOff)*2048 + n]);  K = 1<<lgK
__global__ void wprep_kernel(const float* __restrict__ src,
                             __hip_bfloat16* __restrict__ dst,
                             int lgK, int rowOff) {
    int idx = blockIdx.x * 256 + threadIdx.x;
    int K = 1 << lgK;
    if (idx >= (2048 << lgK)) return;
    int n = idx >> lgK;
    int k = idx & (K - 1);
    dst[idx] = __float2bfloat16(src[(size_t)(k + rowOff) * 2048 + n]);
}

__global__ __launch_bounds__(512, 2)
void lstm_main(const float* __restrict__ x,
               const float* __restrict__ b0v,
               const float* __restrict__ Wx1,     // row 0 = flag weights (f32)
               const float* __restrict__ b1v,
               const float* __restrict__ Wlin,
               const float* __restrict__ blin,
               const __hip_bfloat16* __restrict__ Wx0T,   // [2048][64]
               const __hip_bfloat16* __restrict__ Wh0T,   // [2048][512]
               const __hip_bfloat16* __restrict__ Wx1hT,  // [2048][512] (rows 1..512 of Wx1)
               const __hip_bfloat16* __restrict__ Wh1T,   // [2048][512]
               float* __restrict__ cws,
               float* __restrict__ out)
{
    // LDS: h tiles row-major, row stride 1024B (512 bf16), XOR-swizzled by (row&7)<<4
    __shared__ __align__(16) __hip_bfloat16 h0s[BW * HID];   // 64 KB
    __shared__ __align__(16) __hip_bfloat16 h1s[BW * HID];   // 64 KB
    __shared__ __align__(16) __hip_bfloat16 xs[BW * IN_F];   // 8 KB, row stride 128B
    __shared__ float flags[BW];

    const int tid  = threadIdx.x;
    const int lane = tid & 63;
    const int wid  = tid >> 6;      // 0..7 -> j-group (64 cols each)
    const int l15  = lane & 15;
    const int lq   = lane >> 4;     // 0..3
    const int lq8  = lq * 8;        // element offset in K for A/B frags
    const int lq16 = lq * 16;       // byte offset
    const int wg   = blockIdx.x;
    const size_t bbase = (size_t)wg * BW;

    // zero h LDS
    {
        int4 z; z.x = z.y = z.z = z.w = 0;
        int4* p0 = (int4*)h0s; int4* p1 = (int4*)h1s;
        for (int i = tid; i < BW * HID * 2 / 16; i += 512) { p0[i] = z; p1[i] = z; }
    }

    // fp32 carried hidden state: [sb][rt][r]
    float h0r[4][4][4];
    float h1r[4][4][4];
    #pragma unroll
    for (int a = 0; a < 4; ++a)
        #pragma unroll
        for (int b = 0; b < 4; ++b)
            #pragma unroll
            for (int c = 0; c < 4; ++c) { h0r[a][b][c] = 0.f; h1r[a][b][c] = 0.f; }

    // A-frag row constants per row-tile
    int arow[4], asw[4];
    #pragma unroll
    for (int rt = 0; rt < 4; ++rt) { arow[rt] = rt * 16 + l15; asw[rt] = (arow[rt] & 7) << 4; }

    __syncthreads();

    for (int t = 0; t < T_STEPS; ++t) {
        // ---- stage x_t (bf16, swizzled) + flags ----
        for (int i = tid; i < BW * IN_F; i += 512) {
            int row = i >> 6;
            int k   = i & 63;
            float v = x[(bbase + row) * (T_STEPS * IN_F) + t * IN_F + k];
            int byte = row * 128 + ((2 * k) ^ ((row & 7) << 4));
            *(__hip_bfloat16*)((char*)xs + byte) = __float2bfloat16(v);
        }
        if (tid < BW) flags[tid] = x[(bbase + tid) * (T_STEPS * IN_F) + t * IN_F];
        __syncthreads();

        // ================= Layer 0: g0 = x@Wx0 + h0@Wh0 + b0 =================
        #pragma unroll
        for (int sb = 0; sb < 4; ++sb) {
            const int jb = wid * 64 + sb * 16;
            f32x4 acc[4][4];
            {
                f32x4 zz = {0.f, 0.f, 0.f, 0.f};
                #pragma unroll
                for (int rt = 0; rt < 4; ++rt)
                    #pragma unroll
                    for (int g = 0; g < 4; ++g) acc[rt][g] = zz;
            }
            // x part: K=64 (2 chunks)
            #pragma unroll
            for (int kc = 0; kc < 2; ++kc) {
                const int k32 = kc * 32;
                bf16x8 a[4];
                #pragma unroll
                for (int rt = 0; rt < 4; ++rt) {
                    int byte = arow[rt] * 128 + ((k32 * 2 + lq16) ^ asw[rt]);
                    a[rt] = *(const bf16x8*)((const char*)xs + byte);
                }
                #pragma unroll
                for (int g = 0; g < 4; ++g) {
                    bf16x8 b = *(const bf16x8*)(Wx0T + ((size_t)(g * 512 + jb + l15) << 6) + k32 + lq8);
                    #pragma unroll
                    for (int rt = 0; rt < 4; ++rt)
                        acc[rt][g] = __builtin_amdgcn_mfma_f32_16x16x32_bf16(a[rt], b, acc[rt][g], 0, 0, 0);
                }
            }
            // h0 part: K=512 (16 chunks)
            #pragma unroll 4
            for (int kc = 0; kc < 16; ++kc) {
                const int k32 = kc * 32;
                bf16x8 a[4];
                #pragma unroll
                for (int rt = 0; rt < 4; ++rt) {
                    int byte = arow[rt] * 1024 + ((k32 * 2 + lq16) ^ asw[rt]);
                    a[rt] = *(const bf16x8*)((const char*)h0s + byte);
                }
                #pragma unroll
                for (int g = 0; g < 4; ++g) {
                    bf16x8 b = *(const bf16x8*)(Wh0T + ((size_t)(g * 512 + jb + l15) << 9) + k32 + lq8);
                    #pragma unroll
                    for (int rt = 0; rt < 4; ++rt)
                        acc[rt][g] = __builtin_amdgcn_mfma_f32_16x16x32_bf16(a[rt], b, acc[rt][g], 0, 0, 0);
                }
            }
            // epilogue: gates + fp32 state update
            float bia[4];
            #pragma unroll
            for (int g = 0; g < 4; ++g) bia[g] = b0v[g * 512 + jb + l15];
            #pragma unroll
            for (int rt = 0; rt < 4; ++rt) {
                #pragma unroll
                for (int r = 0; r < 4; ++r) {
                    const int row = rt * 16 + lq * 4 + r;
                    const float flg = flags[row];
                    float gi = acc[rt][0][r] + bia[0];
                    float gf = acc[rt][1][r] + bia[1];
                    float gg = acc[rt][2][r] + bia[2];
                    float go = acc[rt][3][r] + bia[3];
                    const int cidx = (((wg * 2 + 0) * 8 + wid) * 4 + sb) * 1024 + (rt * 4 + r) * 64 + lane;
                    float c_old = 0.f;
                    if (t > 0) c_old = cws[cidx];
                    float cn = fast_sig(gf) * c_old + fast_sig(gi) * fast_tanh(gg);
                    float hn = fast_sig(go) * fast_tanh(cn);
                    cws[cidx] = flg * cn + (1.f - flg) * c_old;
                    h0r[sb][rt][r] = flg * hn + (1.f - flg) * h0r[sb][rt][r];
                }
            }
        }
        __syncthreads();   // everyone done reading old h0s / xs
        // write new h0 -> LDS (bf16, swizzled)
        #pragma unroll
        for (int sb = 0; sb < 4; ++sb)
            #pragma unroll
            for (int rt = 0; rt < 4; ++rt)
                #pragma unroll
                for (int r = 0; r < 4; ++r) {
                    const int row = rt * 16 + lq * 4 + r;
                    const int j = wid * 64 + sb * 16 + l15;
                    const int byte = row * 1024 + ((2 * j) ^ ((row & 7) << 4));
                    *(__hip_bfloat16*)((char*)h0s + byte) = __float2bfloat16(h0r[sb][rt][r]);
                }
        __syncthreads();   // new h0s visible

        // ===== Layer 1: g1 = flag*Wx1[0] + h0_new@Wx1[1:] + h1@Wh1 + b1 =====
        #pragma unroll
        for (int sb = 0; sb < 4; ++sb) {
            const int jb = wid * 64 + sb * 16;
            f32x4 acc[4][4];
            {
                f32x4 zz = {0.f, 0.f, 0.f, 0.f};
                #pragma unroll
                for (int rt = 0; rt < 4; ++rt)
                    #pragma unroll
                    for (int g = 0; g < 4; ++g) acc[rt][g] = zz;
            }
            #pragma unroll 4
            for (int kc = 0; kc < 16; ++kc) {   // h0_new @ Wx1h
                const int k32 = kc * 32;
                bf16x8 a[4];
                #pragma unroll
                for (int rt = 0; rt < 4; ++rt) {
                    int byte = arow[rt] * 1024 + ((k32 * 2 + lq16) ^ asw[rt]);
                    a[rt] = *(const bf16x8*)((const char*)h0s + byte);
                }
                #pragma unroll
                for (int g = 0; g < 4; ++g) {
                    bf16x8 b = *(const bf16x8*)(Wx1hT + ((size_t)(g * 512 + jb + l15) << 9) + k32 + lq8);
                    #pragma unroll
                    for (int rt = 0; rt < 4; ++rt)
                        acc[rt][g] = __builtin_amdgcn_mfma_f32_16x16x32_bf16(a[rt], b, acc[rt][g], 0, 0, 0);
                }
            }
            #pragma unroll 4
            for (int kc = 0; kc < 16; ++kc) {   // h1_old @ Wh1
                const int k32 = kc * 32;
                bf16x8 a[4];
                #pragma unroll
                for (int rt = 0; rt < 4; ++rt) {
                    int byte = arow[rt] * 1024 + ((k32 * 2 + lq16) ^ asw[rt]);
                    a[rt] = *(const bf16x8*)((const char*)h1s + byte);
                }
                #pragma unroll
                for (int g = 0; g < 4; ++g) {
                    bf16x8 b = *(const bf16x8*)(Wh1T + ((size_t)(g * 512 + jb + l15) << 9) + k32 + lq8);
                    #pragma unroll
                    for (int rt = 0; rt < 4; ++rt)
                        acc[rt][g] = __builtin_amdgcn_mfma_f32_16x16x32_bf16(a[rt], b, acc[rt][g], 0, 0, 0);
                }
            }
            float bia[4], w10[4];
            #pragma unroll
            for (int g = 0; g < 4; ++g) {
                bia[g] = b1v[g * 512 + jb + l15];
                w10[g] = Wx1[g * 512 + jb + l15];   // Wx1 row 0 (flag column weights)
            }
            #pragma unroll
            for (int rt = 0; rt < 4; ++rt) {
                #pragma unroll
                for (int r = 0; r < 4; ++r) {
                    const int row = rt * 16 + lq * 4 + r;
                    const float flg = flags[row];
                    float gi = acc[rt][0][r] + bia[0] + flg * w10[0];
                    float gf = acc[rt][1][r] + bia[1] + flg * w10[1];
                    float gg = acc[rt][2][r] + bia[2] + flg * w10[2];
                    float go = acc[rt][3][r] + bia[3] + flg * w10[3];
                    const int cidx = (((wg * 2 + 1) * 8 + wid) * 4 + sb) * 1024 + (rt * 4 + r) * 64 + lane;
                    float c_old = 0.f;
                    if (t > 0) c_old = cws[cidx];
                    float cn = fast_sig(gf) * c_old + fast_sig(gi) * fast_tanh(gg);
                    float hn = fast_sig(go) * fast_tanh(cn);
                    cws[cidx] = flg * cn + (1.f - flg) * c_old;
                    h1r[sb][rt][r] = flg * hn + (1.f - flg) * h1r[sb][rt][r];
                }
            }
        }
        __syncthreads();   // done reading old h1s
        #pragma unroll
        for (int sb = 0; sb < 4; ++sb)
            #pragma unroll
            for (int rt = 0; rt < 4; ++rt)
                #pragma unroll
                for (int r = 0; r < 4; ++r) {
                    const int row = rt * 16 + lq * 4 + r;
                    const int j = wid * 64 + sb * 16 + l15;
                    const int byte = row * 1024 + ((2 * j) ^ ((row & 7) << 4));
                    *(__hip_bfloat16*)((char*)h1s + byte) = __float2bfloat16(h1r[sb][rt][r]);
                }
        __syncthreads();   // new h1s visible for next step
    }

    // ---- final linear: out = h1 @ Wlin + blin  (64x512 @ 512x19) ----
    for (int task = tid; task < BW * OUT_F; task += 512) {
        int o   = task >> 6;     // 0..18, wave-uniform
        int row = task & 63;
        float s = blin[o];
        const float* wl = Wlin + o;
        for (int k = 0; k < HID; ++k) {
            int byte = row * 1024 + ((2 * k) ^ ((row & 7) << 4));
            float hv = __bfloat162float(*(const __hip_bfloat16*)((const char*)h1s + byte));
            s += hv * wl[k * OUT_F];
        }
        out[(bbase + row) * OUT_F + o] = s;
    }
}

extern "C" void kernel_launch(void* const* d_in, const int* in_sizes, int n_in,
                              void* d_out, int out_size, void* d_ws, size_t ws_size,
                              hipStream_t stream) {
    const float* x    = (const float*)d_in[0];
    const float* Wx0  = (const float*)d_in[1];
    const float* Wh0  = (const float*)d_in[2];
    const float* b0   = (const float*)d_in[3];
    const float* Wx1  = (const float*)d_in[4];
    const float* Wh1  = (const float*)d_in[5];
    const float* b1   = (const float*)d_in[6];
    const float* Wlin = (const float*)d_in[7];
    const float* blin = (const float*)d_in[8];
    // d_in[9] = time_step (=32, compile-time constant here)

    // workspace carve (bytes)
    const size_t offWx0T  = 0;                       // 2048*64*2   = 262144
    const size_t offWh0T  = 262144;                  // 2048*512*2  = 2097152
    const size_t offWx1hT = 2359296;
    const size_t offWh1T  = 4456448;
    const size_t offC     = 6553600;                 // 256*65536*4 = 67108864
    const size_t needed   = 73662464;
    if (ws_size < needed) return;

    char* w = (char*)d_ws;
    __hip_bfloat16* Wx0T  = (__hip_bfloat16*)(w + offWx0T);
    __hip_bfloat16* Wh0T  = (__hip_bfloat16*)(w + offWh0T);
    __hip_bfloat16* Wx1hT = (__hip_bfloat16*)(w + offWx1hT);
    __hip_bfloat16* Wh1T  = (__hip_bfloat16*)(w + offWh1T);
    float* cws = (float*)(w + offC);

    dim3 blk(256);
    wprep_kernel<<<(2048 * 64 + 255) / 256, blk, 0, stream>>>(Wx0, Wx0T, 6, 0);
    wprep_kernel<<<(2048 * 512 + 255) / 256, blk, 0, stream>>>(Wh0, Wh0T, 9, 0);
    wprep_kernel<<<(2048 * 512 + 255) / 256, blk, 0, stream>>>(Wx1, Wx1hT, 9, 1);  // skip flag row
    wprep_kernel<<<(2048 * 512 + 255) / 256, blk, 0, stream>>>(Wh1, Wh1T, 9, 0);

    lstm_main<<<256, 512, 0, stream>>>(x, b0, Wx1, b1, Wlin, blin,
                                       Wx0T, Wh0T, Wx1hT, Wh1T, cws, (float*)d_out);
}

// Round 2
// 10319.330 us; speedup vs baseline: 1.7449x; 1.7449x over previous
//
#include <hip/hip_runtime.h>
#include <hip/hip_bf16.h>

// SSNet: 2-layer flag-gated LSTM, persistent-tile MFMA implementation.
// B=16384, T=32, IN=64, H=512, OUT=19.
// One WG (512 thr, 8 waves) per 64 batch rows; 256 WGs = 256 CUs.
// R2 change: fp32 h/c state streamed through global workspace (prefetched
// per sub-block, consumed in epilogue) instead of persistent VGPR arrays,
// which were spilling to scratch (R1: VGPR=128 + ~8GB scratch traffic).

#define T_STEPS 32
#define IN_F    64
#define HID     512
#define OUT_F   19
#define BW      64   // batch rows per WG

typedef short bf16x8 __attribute__((ext_vector_type(8)));   // 8 bf16 = 4 VGPRs
typedef float f32x4  __attribute__((ext_vector_type(4)));

__device__ __forceinline__ float fast_sig(float x) {
    return __builtin_amdgcn_rcpf(1.0f + __expf(-x));
}
__device__ __forceinline__ float fast_tanh(float x) {
    return 1.0f - 2.0f * __builtin_amdgcn_rcpf(1.0f + __expf(2.0f * x));
}

// dst[n*K + k] = bf16(src[(k+rowOff)*2048 + n]);  K = 1<<lgK
__global__ void wprep_kernel(const float* __restrict__ src,
                             __hip_bfloat16* __restrict__ dst,
                             int lgK, int rowOff) {
    int idx = blockIdx.x * 256 + threadIdx.x;
    int K = 1 << lgK;
    if (idx >= (2048 << lgK)) return;
    int n = idx >> lgK;
    int k = idx & (K - 1);
    dst[idx] = __float2bfloat16(src[(size_t)(k + rowOff) * 2048 + n]);
}

// K-chunk GEMM accumulate: acc[rt][g] += A(lds) x B(global), 16x16x32 bf16 MFMA.
template<int KCHUNKS, int ROWSTRIDE>
__device__ __forceinline__ void gemm_acc(const char* __restrict__ alds,
                                         const __hip_bfloat16* __restrict__ Bt,
                                         f32x4 acc[4][4],
                                         const int arow[4], const int asw[4],
                                         int l15, int lq16, int lq8, int jb) {
    #pragma unroll 2
    for (int kc = 0; kc < KCHUNKS; ++kc) {
        const int k32 = kc * 32;
        bf16x8 a[4];
        #pragma unroll
        for (int rt = 0; rt < 4; ++rt) {
            int byte = arow[rt] * ROWSTRIDE + ((k32 * 2 + lq16) ^ asw[rt]);
            a[rt] = *(const bf16x8*)(alds + byte);
        }
        #pragma unroll
        for (int g = 0; g < 4; ++g) {
            bf16x8 b = *(const bf16x8*)(Bt + (size_t)(g * 512 + jb + l15) * (KCHUNKS * 32) + k32 + lq8);
            #pragma unroll
            for (int rt = 0; rt < 4; ++rt)
                acc[rt][g] = __builtin_amdgcn_mfma_f32_16x16x32_bf16(a[rt], b, acc[rt][g], 0, 0, 0);
        }
    }
}

__global__ __launch_bounds__(512, 2)
void lstm_main(const float* __restrict__ x,
               const float* __restrict__ b0v,
               const float* __restrict__ Wx1,     // row 0 = flag weights (f32)
               const float* __restrict__ b1v,
               const float* __restrict__ Wlin,
               const float* __restrict__ blin,
               const __hip_bfloat16* __restrict__ Wx0T,   // [2048][64]
               const __hip_bfloat16* __restrict__ Wh0T,   // [2048][512]
               const __hip_bfloat16* __restrict__ Wx1hT,  // [2048][512] (rows 1..512 of Wx1)
               const __hip_bfloat16* __restrict__ Wh1T,   // [2048][512]
               float* __restrict__ cws,
               float* __restrict__ hws,
               float* __restrict__ out)
{
    // LDS: h tiles row-major bf16, row stride 1024B, XOR-swizzled by (row&7)<<4
    __shared__ __align__(16) __hip_bfloat16 h0s[BW * HID];   // 64 KB
    __shared__ __align__(16) __hip_bfloat16 h1s[BW * HID];   // 64 KB
    __shared__ __align__(16) __hip_bfloat16 xs[BW * IN_F];   // 8 KB, row stride 128B
    __shared__ float flags[BW];

    const int tid  = threadIdx.x;
    const int lane = tid & 63;
    const int wid  = tid >> 6;      // 0..7 -> j-group (64 cols each)
    const int l15  = lane & 15;
    const int lq   = lane >> 4;     // 0..3
    const int lq8  = lq * 8;
    const int lq16 = lq * 16;
    const int wg   = blockIdx.x;
    const size_t bbase = (size_t)wg * BW;

    // zero h LDS
    {
        int4 z; z.x = z.y = z.z = z.w = 0;
        int4* p0 = (int4*)h0s; int4* p1 = (int4*)h1s;
        for (int i = tid; i < BW * HID * 2 / 16; i += 512) { p0[i] = z; p1[i] = z; }
    }

    // A-frag row constants per row-tile
    int arow[4], asw[4];
    #pragma unroll
    for (int rt = 0; rt < 4; ++rt) { arow[rt] = rt * 16 + l15; asw[rt] = (arow[rt] & 7) << 4; }

    // per-step new-h register block for the deferred LDS write (one layer at a time)
    f32x4 hnr[4][4];   // [sb][rt], 64 VGPRs

    __syncthreads();

    for (int t = 0; t < T_STEPS; ++t) {
        // ---- stage x_t (bf16, swizzled) + flags ----
        for (int i = tid; i < BW * IN_F; i += 512) {
            int row = i >> 6;
            int k   = i & 63;
            float v = x[(bbase + row) * (T_STEPS * IN_F) + t * IN_F + k];
            int byte = row * 128 + ((2 * k) ^ ((row & 7) << 4));
            *(__hip_bfloat16*)((char*)xs + byte) = __float2bfloat16(v);
        }
        if (tid < BW) flags[tid] = x[(bbase + tid) * (T_STEPS * IN_F) + t * IN_F];
        __syncthreads();

        // ================= Layer 0: g0 = x@Wx0 + h0@Wh0 + b0 =================
        #pragma unroll
        for (int sb = 0; sb < 4; ++sb) {
            const int jb = wid * 64 + sb * 16;
            const size_t sb_base = (size_t)((((wg * 2 + 0) * 8 + wid) * 4 + sb) * 4) * 256 + lane * 4;

            // prefetch old fp32 state (consumed in epilogue; hides under GEMM)
            f32x4 cold[4], hold[4];
            if (t > 0) {
                #pragma unroll
                for (int rt = 0; rt < 4; ++rt) {
                    cold[rt] = *(const f32x4*)(cws + sb_base + rt * 256);
                    hold[rt] = *(const f32x4*)(hws + sb_base + rt * 256);
                }
            } else {
                f32x4 zz = {0.f, 0.f, 0.f, 0.f};
                #pragma unroll
                for (int rt = 0; rt < 4; ++rt) { cold[rt] = zz; hold[rt] = zz; }
            }

            f32x4 acc[4][4];
            {
                f32x4 zz = {0.f, 0.f, 0.f, 0.f};
                #pragma unroll
                for (int rt = 0; rt < 4; ++rt)
                    #pragma unroll
                    for (int g = 0; g < 4; ++g) acc[rt][g] = zz;
            }
            gemm_acc<2, 128>((const char*)xs,  Wx0T, acc, arow, asw, l15, lq16, lq8, jb);
            gemm_acc<16, 1024>((const char*)h0s, Wh0T, acc, arow, asw, l15, lq16, lq8, jb);

            float bia[4];
            #pragma unroll
            for (int g = 0; g < 4; ++g) bia[g] = b0v[g * 512 + jb + l15];
            #pragma unroll
            for (int rt = 0; rt < 4; ++rt) {
                f32x4 cnew, hnew;
                #pragma unroll
                for (int r = 0; r < 4; ++r) {
                    const int row = rt * 16 + lq * 4 + r;
                    const float flg = flags[row];
                    float gi = acc[rt][0][r] + bia[0];
                    float gf = acc[rt][1][r] + bia[1];
                    float gg = acc[rt][2][r] + bia[2];
                    float go = acc[rt][3][r] + bia[3];
                    float c_old = cold[rt][r];
                    float h_old = hold[rt][r];
                    float cn = fast_sig(gf) * c_old + fast_sig(gi) * fast_tanh(gg);
                    float hn = fast_sig(go) * fast_tanh(cn);
                    cnew[r] = flg * cn + (1.f - flg) * c_old;
                    hnew[r] = flg * hn + (1.f - flg) * h_old;
                }
                *(f32x4*)(cws + sb_base + rt * 256) = cnew;
                *(f32x4*)(hws + sb_base + rt * 256) = hnew;
                hnr[sb][rt] = hnew;
            }
        }
        __syncthreads();   // everyone done reading old h0s / xs
        // write new h0 -> LDS (bf16, swizzled)
        #pragma unroll
        for (int sb = 0; sb < 4; ++sb)
            #pragma unroll
            for (int rt = 0; rt < 4; ++rt)
                #pragma unroll
                for (int r = 0; r < 4; ++r) {
                    const int row = rt * 16 + lq * 4 + r;
                    const int j = wid * 64 + sb * 16 + l15;
                    const int byte = row * 1024 + ((2 * j) ^ ((row & 7) << 4));
                    *(__hip_bfloat16*)((char*)h0s + byte) = __float2bfloat16(hnr[sb][rt][r]);
                }
        __syncthreads();   // new h0s visible

        // ===== Layer 1: g1 = flag*Wx1[0] + h0_new@Wx1[1:] + h1@Wh1 + b1 =====
        #pragma unroll
        for (int sb = 0; sb < 4; ++sb) {
            const int jb = wid * 64 + sb * 16;
            const size_t sb_base = (size_t)((((wg * 2 + 1) * 8 + wid) * 4 + sb) * 4) * 256 + lane * 4;

            f32x4 cold[4], hold[4];
            if (t > 0) {
                #pragma unroll
                for (int rt = 0; rt < 4; ++rt) {
                    cold[rt] = *(const f32x4*)(cws + sb_base + rt * 256);
                    hold[rt] = *(const f32x4*)(hws + sb_base + rt * 256);
                }
            } else {
                f32x4 zz = {0.f, 0.f, 0.f, 0.f};
                #pragma unroll
                for (int rt = 0; rt < 4; ++rt) { cold[rt] = zz; hold[rt] = zz; }
            }

            f32x4 acc[4][4];
            {
                f32x4 zz = {0.f, 0.f, 0.f, 0.f};
                #pragma unroll
                for (int rt = 0; rt < 4; ++rt)
                    #pragma unroll
                    for (int g = 0; g < 4; ++g) acc[rt][g] = zz;
            }
            gemm_acc<16, 1024>((const char*)h0s, Wx1hT, acc, arow, asw, l15, lq16, lq8, jb);
            gemm_acc<16, 1024>((const char*)h1s, Wh1T, acc, arow, asw, l15, lq16, lq8, jb);

            float bia[4], w10[4];
            #pragma unroll
            for (int g = 0; g < 4; ++g) {
                bia[g] = b1v[g * 512 + jb + l15];
                w10[g] = Wx1[g * 512 + jb + l15];   // Wx1 row 0 (flag column weights)
            }
            #pragma unroll
            for (int rt = 0; rt < 4; ++rt) {
                f32x4 cnew, hnew;
                #pragma unroll
                for (int r = 0; r < 4; ++r) {
                    const int row = rt * 16 + lq * 4 + r;
                    const float flg = flags[row];
                    float gi = acc[rt][0][r] + bia[0] + flg * w10[0];
                    float gf = acc[rt][1][r] + bia[1] + flg * w10[1];
                    float gg = acc[rt][2][r] + bia[2] + flg * w10[2];
                    float go = acc[rt][3][r] + bia[3] + flg * w10[3];
                    float c_old = cold[rt][r];
                    float h_old = hold[rt][r];
                    float cn = fast_sig(gf) * c_old + fast_sig(gi) * fast_tanh(gg);
                    float hn = fast_sig(go) * fast_tanh(cn);
                    cnew[r] = flg * cn + (1.f - flg) * c_old;
                    hnew[r] = flg * hn + (1.f - flg) * h_old;
                }
                *(f32x4*)(cws + sb_base + rt * 256) = cnew;
                *(f32x4*)(hws + sb_base + rt * 256) = hnew;
                hnr[sb][rt] = hnew;
            }
        }
        __syncthreads();   // done reading old h1s
        #pragma unroll
        for (int sb = 0; sb < 4; ++sb)
            #pragma unroll
            for (int rt = 0; rt < 4; ++rt)
                #pragma unroll
                for (int r = 0; r < 4; ++r) {
                    const int row = rt * 16 + lq * 4 + r;
                    const int j = wid * 64 + sb * 16 + l15;
                    const int byte = row * 1024 + ((2 * j) ^ ((row & 7) << 4));
                    *(__hip_bfloat16*)((char*)h1s + byte) = __float2bfloat16(hnr[sb][rt][r]);
                }
        __syncthreads();   // new h1s visible for next step
    }

    // ---- final linear: out = h1 @ Wlin + blin  (64x512 @ 512x19) ----
    for (int task = tid; task < BW * OUT_F; task += 512) {
        int o   = task >> 6;     // 0..18, wave-uniform
        int row = task & 63;
        float s = blin[o];
        const float* wl = Wlin + o;
        for (int k = 0; k < HID; ++k) {
            int byte = row * 1024 + ((2 * k) ^ ((row & 7) << 4));
            float hv = __bfloat162float(*(const __hip_bfloat16*)((const char*)h1s + byte));
            s += hv * wl[k * OUT_F];
        }
        out[(bbase + row) * OUT_F + o] = s;
    }
}

extern "C" void kernel_launch(void* const* d_in, const int* in_sizes, int n_in,
                              void* d_out, int out_size, void* d_ws, size_t ws_size,
                              hipStream_t stream) {
    const float* x    = (const float*)d_in[0];
    const float* Wx0  = (const float*)d_in[1];
    const float* Wh0  = (const float*)d_in[2];
    const float* b0   = (const float*)d_in[3];
    const float* Wx1  = (const float*)d_in[4];
    const float* Wh1  = (const float*)d_in[5];
    const float* b1   = (const float*)d_in[6];
    const float* Wlin = (const float*)d_in[7];
    const float* blin = (const float*)d_in[8];

    // workspace carve (bytes)
    const size_t offWx0T  = 0;                       // 2048*64*2   = 262144
    const size_t offWh0T  = 262144;                  // 2048*512*2  = 2097152
    const size_t offWx1hT = 2359296;
    const size_t offWh1T  = 4456448;
    const size_t offC     = 6553600;                 // 256*65536*4 = 67108864
    const size_t offH     = 73662464;                // 256*65536*4 = 67108864
    const size_t needed   = 140771328;
    if (ws_size < needed) return;

    char* w = (char*)d_ws;
    __hip_bfloat16* Wx0T  = (__hip_bfloat16*)(w + offWx0T);
    __hip_bfloat16* Wh0T  = (__hip_bfloat16*)(w + offWh0T);
    __hip_bfloat16* Wx1hT = (__hip_bfloat16*)(w + offWx1hT);
    __hip_bfloat16* Wh1T  = (__hip_bfloat16*)(w + offWh1T);
    float* cws = (float*)(w + offC);
    float* hws = (float*)(w + offH);

    dim3 blk(256);
    wprep_kernel<<<(2048 * 64 + 255) / 256, blk, 0, stream>>>(Wx0, Wx0T, 6, 0);
    wprep_kernel<<<(2048 * 512 + 255) / 256, blk, 0, stream>>>(Wh0, Wh0T, 9, 0);
    wprep_kernel<<<(2048 * 512 + 255) / 256, blk, 0, stream>>>(Wx1, Wx1hT, 9, 1);  // skip flag row
    wprep_kernel<<<(2048 * 512 + 255) / 256, blk, 0, stream>>>(Wh1, Wh1T, 9, 0);

    lstm_main<<<256, 512, 0, stream>>>(x, b0, Wx1, b1, Wlin, blin,
                                       Wx0T, Wh0T, Wx1hT, Wh1T, cws, hws, (float*)d_out);
}